// Round 2
// baseline (729.153 us; speedup 1.0000x reference)
//
#include <hip/hip_runtime.h>

// LogicVAE: graph-GRU VAE encoder. B=2048,N=32,V=10,H=256,Z=64.
// gm[b,n] = sigmoid(h@w_gate+b_gate)*(h@w_map) is a pure function of the FINAL
// hidden[b,n] (adj strictly upper-tri), so it's computed once per node.
// R7 vs R6 (479us): counters showed WRITE=91MB (~scratch) with VGPR_Count=64:
// launch_bounds(1024,4) caps unified VGPR/AGPR at 128/thread, so R5/R6's
// "pinned" wG/wM tiles were SPILLED and re-read from scratch every step
// (~4.2GB L2 volume) on top of the whh stream (3.1GB; M=8 of M=16 wasted).
//  - BT=16: full M=16 MFMA rows -> weight stream per batch HALVES (128 blocks)
//  - 512-thread blocks, launch_bounds(512,2): 2 waves/SIMD -> 256-reg budget;
//    4 wgm tiles (128 regs) genuinely pinned; each wave runs 2 w_hh triplets
//  - gm state back in global (nt loads/stores, ~100MB total) with R5-proven
//    gmrow LDS staging of the newest row; LDS now only ~49KB

#define BB 2048
#define NN 32
#define VV 10
#define HH 256
#define ZZ 64
#define BT 16     // batches per block (full MFMA M=16)
#define KC 8      // K chunks: 256/32
#define NT1 48    // 768/16 col tiles (w_hh)
#define NT2 32    // 512/16 col tiles (w_gate||w_map)
#define WHH_ELEMS (NT1 * KC * 64 * 8)             // 196608 ushorts (384 KB)
#define WGM_ELEMS (NT2 * KC * 64 * 8)             // 131072 ushorts (256 KB)
#define WIH_BYTES (VV * 768 * 4)                  // 30720 B fp32 folded table
#define GM_BYTE_OFF ((WHH_ELEMS + WGM_ELEMS) * 2 + WIH_BYTES) // 686080
#define SLAB_ELEMS (BT * NN * HH)                 // 131072 ushorts
#define SLAB_BYTES (SLAB_ELEMS * 2)               // 262144 B

typedef __attribute__((ext_vector_type(8))) short frag8;            // 8 bf16 (4 VGPR)
typedef __attribute__((ext_vector_type(4))) float facc4;            // MFMA accum
typedef __attribute__((ext_vector_type(4))) unsigned short us4;     // 8B vector

__device__ __forceinline__ float bf2f(unsigned short u) {
    unsigned int x = ((unsigned int)u) << 16;
    return __builtin_bit_cast(float, x);
}
__device__ __forceinline__ unsigned short f2bf(float f) {
    unsigned int x = __builtin_bit_cast(unsigned int, f);
    x += 0x7FFFu + ((x >> 16) & 1u);
    return (unsigned short)(x >> 16);
}
__device__ __forceinline__ float sigm(float x) { return 1.0f / (1.0f + __expf(-x)); }
__device__ __forceinline__ float ldv(const float* p, size_t i) { return p[i]; }
__device__ __forceinline__ float ldv(const unsigned short* p, size_t i) { return bf2f(p[i]); }
__device__ __forceinline__ void stv(float* p, size_t i, float v) { p[i] = v; }
__device__ __forceinline__ void stv(unsigned short* p, size_t i, float v) { p[i] = f2bf(v); }
__device__ __forceinline__ us4 ntld4(const unsigned short* p) {
    return __builtin_nontemporal_load((const us4*)p);
}
__device__ __forceinline__ void ntst4(unsigned short* p, us4 v) {
    __builtin_nontemporal_store(v, (us4*)p);
}

// flag=1 => buffers are fp32, flag=0 => bf16. Integer-only tests (fast-math safe).
__global__ void detect_dtype(const unsigned short* __restrict__ w, int* flag) {
    __shared__ int zc, bc;
    if (threadIdx.x == 0) { zc = 0; bc = 0; }
    __syncthreads();
    int z = 0, b = 0;
    for (int i = threadIdx.x; i < 2048; i += 256) {
        unsigned short lo = w[2 * i];            // fp32: low mantissa half / bf16: a value
        if (lo == 0) z++;                        // bf16-rounded fp32 storage => all zero
        unsigned e = (lo >> 7) & 0xFFu;          // bf16 exponent field
        if (e >= 0x86u) b++;                     // |x|>=128 or NaN: impossible for N(0,.05) bf16
    }
    atomicAdd(&zc, z); atomicAdd(&bc, b);
    __syncthreads();
    if (threadIdx.x == 0) *flag = (bc > 0 || zc > 512) ? 1 : 0;
}

// Repack w_hh (256x768) and w_gate||w_map (256x512) into bf16 MFMA B-fragment
// order: frag f=jt*KC+kc; elem[(f*64+lane)*8+j] = W[kc*32+(lane>>4)*8+j][jt*16+(lane&15)]
// Tail threads build wihG[10][768] = fp32(w_ih + b_ih) folded table.
template <typename T>
__global__ void repack_weights(const T* __restrict__ w_hh,
                               const T* __restrict__ w_gate,
                               const T* __restrict__ w_map,
                               const T* __restrict__ w_ih,
                               const T* __restrict__ b_ih,
                               unsigned short* __restrict__ whh_p,
                               unsigned short* __restrict__ wgm_p,
                               float* __restrict__ wihG,
                               const int* __restrict__ flag, int want) {
    if (*flag != want) return;
    int t = blockIdx.x * blockDim.x + threadIdx.x;
    int lane = t & 63;
    int frag = t >> 6;                  // 0..759
    int kbase = (lane >> 4) * 8;
    if (frag < NT1 * KC) {
        int jt = frag / KC, kc = frag % KC;
        int col = jt * 16 + (lane & 15);
        unsigned short* dst = whh_p + ((size_t)frag * 64 + lane) * 8;
        #pragma unroll
        for (int j = 0; j < 8; ++j)
            dst[j] = f2bf(ldv(w_hh, (size_t)(kc * 32 + kbase + j) * 768 + col));
    } else if (frag < (NT1 + NT2) * KC) {
        int f2 = frag - NT1 * KC;
        int jt = f2 / KC, kc = f2 % KC;
        int col = jt * 16 + (lane & 15);
        unsigned short* dst = wgm_p + ((size_t)f2 * 64 + lane) * 8;
        #pragma unroll
        for (int j = 0; j < 8; ++j) {
            int k = kc * 32 + kbase + j;
            dst[j] = f2bf((col < HH) ? ldv(w_gate, (size_t)k * HH + col)
                                     : ldv(w_map, (size_t)k * HH + (col - HH)));
        }
    } else {
        int idx = t - (NT1 + NT2) * KC * 64;     // 0..7679 with grid=190
        if (idx < VV * 768) {
            int c = idx % 768;
            wihG[idx] = ldv(w_ih, (size_t)idx) + ldv(b_ih, (size_t)c);
        }
    }
}

template <typename T>
__global__ __launch_bounds__(512, 2) void vae_main(
    const T* __restrict__ adj,
    const int* __restrict__ ntypes,
    const T* __restrict__ b_hh,
    const T* __restrict__ b_gate,
    const T* __restrict__ w_mu,
    const T* __restrict__ b_mu,
    const T* __restrict__ w_std,
    const T* __restrict__ b_std,
    const unsigned short* __restrict__ whh_p,
    const unsigned short* __restrict__ wgm_p,
    const float* __restrict__ wihG,
    unsigned short* __restrict__ gm_base,
    T* __restrict__ out,
    int b_start,
    const int* __restrict__ flag, int want)
{
    if (*flag != want) return;

    __shared__ __align__(16) unsigned short gmrow[BT][HH];  // newest gm row (8 KB)
    __shared__ __align__(16) float agg[BT][HH];             // fp32 agg (16 KB)
    __shared__ __align__(16) unsigned short aggbf[16][264]; // MFMA A src (8.4 KB)
    __shared__ __align__(16) unsigned short hnew[16][264];  // MFMA A src (8.4 KB)
    __shared__ unsigned int  amask[BT][NN];                 // adj bitmasks (2 KB)
    __shared__ int           ntva[BT][NN];                  // node types (2 KB)
    __shared__ __align__(16) float bhhL[768];               // b_hh (3 KB)
    __shared__ float bgL[HH];                               // b_gate (1 KB)

    const int tid  = threadIdx.x;
    const int lane = tid & 63;
    const int w    = tid >> 6;          // wave 0..7
    const int b0   = b_start + blockIdx.x * BT;

    unsigned short* gms = gm_base + (size_t)blockIdx.x * SLAB_ELEMS;  // per-block slab

    const frag8* whh8 = (const frag8*)whh_p;
    const frag8* wgm8 = (const frag8*)wgm_p;

    // ---- one-time preload (512 threads) ----
    {
        int bi = tid >> 5, vv = tid & 31;    // covers all 16 batches
        unsigned m = 0;
        for (int n = 0; n < NN; ++n)
            if (ldv(adj, ((size_t)(b0 + bi) * NN + n) * NN + vv) != 0.0f) m |= (1u << n);
        amask[bi][vv] = m;
        ntva[bi][vv] = ntypes[(b0 + bi) * NN + vv];
    }
    for (int i = tid; i < 768; i += 512) bhhL[i] = ldv(b_hh, i);
    if (tid < HH) bgL[tid] = ldv(b_gate, tid);

    // ---- pin phase-D tiles in regs for all 32 steps: gate {w,w+8}, map {w+16,w+24}
    frag8 wG0[KC], wG1[KC], wM0[KC], wM1[KC];
    {
        const frag8* p0 = wgm8 + (size_t)(w     ) * (KC * 64) + lane;
        const frag8* p1 = wgm8 + (size_t)(w +  8) * (KC * 64) + lane;
        const frag8* p2 = wgm8 + (size_t)(w + 16) * (KC * 64) + lane;
        const frag8* p3 = wgm8 + (size_t)(w + 24) * (KC * 64) + lane;
        #pragma unroll
        for (int kc = 0; kc < KC; ++kc) {
            wG0[kc] = p0[kc * 64]; wG1[kc] = p1[kc * 64];
            wM0[kc] = p2[kc * 64]; wM1[kc] = p3[kc * 64];
        }
    }
    __syncthreads();

    for (int v = 0; v < NN; ++v) {
        // ---- A: each wave aggregates 2 batches; newest row (v-1) from LDS;
        //         older rows nt-loaded from the global slab. Also writes row
        //         v-1 out to global (gmrow gets overwritten by phase D).
        {
            const int h4 = lane * 4;
            #pragma unroll
            for (int s = 0; s < 2; ++s) {
                const int bi = 2 * w + s;
                unsigned m0 = amask[bi][v];              // wave-uniform
                unsigned m  = (v > 0) ? (m0 & ~(1u << (v - 1))) : m0;
                float a0 = 0.f, a1 = 0.f, a2 = 0.f, a3 = 0.f;
                const unsigned short* rb = gms + (size_t)bi * NN * HH + h4;
                while (m) {                              // 2-wide: 2 loads in flight
                    const int n0 = __builtin_ctz(m); m &= m - 1;
                    const us4 g0 = ntld4(rb + (size_t)n0 * HH);
                    if (m) {
                        const int n1 = __builtin_ctz(m); m &= m - 1;
                        const us4 g1 = ntld4(rb + (size_t)n1 * HH);
                        a0 += bf2f(g0.x) + bf2f(g1.x);
                        a1 += bf2f(g0.y) + bf2f(g1.y);
                        a2 += bf2f(g0.z) + bf2f(g1.z);
                        a3 += bf2f(g0.w) + bf2f(g1.w);
                    } else {
                        a0 += bf2f(g0.x); a1 += bf2f(g0.y);
                        a2 += bf2f(g0.z); a3 += bf2f(g0.w);
                    }
                }
                if (v > 0) {
                    const us4 gr = *(const us4*)&gmrow[bi][h4];
                    if ((m0 >> (v - 1)) & 1u) {          // newest row: from LDS
                        a0 += bf2f(gr.x); a1 += bf2f(gr.y);
                        a2 += bf2f(gr.z); a3 += bf2f(gr.w);
                    }
                    // write-out row v-1 (512B/batch, 8B/lane, nt: keep L2 for whh)
                    ntst4(gms + ((size_t)bi * NN + (v - 1)) * HH + h4, gr);
                }
                *(float4*)&agg[bi][h4] = make_float4(a0, a1, a2, a3);
                ushort4 ab; ab.x = f2bf(a0); ab.y = f2bf(a1); ab.z = f2bf(a2); ab.w = f2bf(a3);
                *(ushort4*)&aggbf[bi][h4] = ab;
            }
        }
        __syncthreads();

        // ---- B: gh = agg @ w_hh (2 triplets/wave) fused with GRU -> hnew
        {
            frag8 afrag[KC];
            #pragma unroll
            for (int kc = 0; kc < KC; ++kc)
                afrag[kc] = *(const frag8*)&aggbf[lane & 15][kc * 32 + (lane >> 4) * 8];

            #pragma unroll
            for (int s = 0; s < 2; ++s) {
                const int t = w + 8 * s;                 // triplet: cols t, t+16, t+32
                facc4 aR = {0.f, 0.f, 0.f, 0.f};
                facc4 aZ = {0.f, 0.f, 0.f, 0.f};
                facc4 aN = {0.f, 0.f, 0.f, 0.f};
                const frag8* pR = whh8 + (size_t)(t     ) * (KC * 64) + lane;
                const frag8* pZ = whh8 + (size_t)(t + 16) * (KC * 64) + lane;
                const frag8* pN = whh8 + (size_t)(t + 32) * (KC * 64) + lane;
                #pragma unroll
                for (int kc = 0; kc < KC; ++kc) {
                    aR = __builtin_amdgcn_mfma_f32_16x16x32_bf16(afrag[kc], pR[kc * 64], aR, 0, 0, 0);
                    aZ = __builtin_amdgcn_mfma_f32_16x16x32_bf16(afrag[kc], pZ[kc * 64], aZ, 0, 0, 0);
                    aN = __builtin_amdgcn_mfma_f32_16x16x32_bf16(afrag[kc], pN[kc * 64], aN, 0, 0, 0);
                }
                const int col = t * 16 + (lane & 15);
                const int q = lane >> 4;                 // C row = 4q+i, all valid
                const float bhr = bhhL[col], bhz = bhhL[col + 256], bhn = bhhL[col + 512];
                #pragma unroll
                for (int i = 0; i < 4; ++i) {
                    const int bi = 4 * q + i;
                    const float* wr = wihG + (size_t)ntva[bi][v] * 768 + col;
                    const float r = sigm(wr[0]   + aR[i] + bhr);
                    const float z = sigm(wr[256] + aZ[i] + bhz);
                    const float n = tanhf(wr[512] + r * (aN[i] + bhn));
                    hnew[bi][col] = f2bf((1.f - z) * n + z * agg[bi][col]);
                }
            }
        }
        __syncthreads();

        // ---- D: gm_v = sigmoid(h@w_gate+b_gate)*(h@w_map) -> gmrow (pinned tiles)
        {
            frag8 hfrag[KC];
            #pragma unroll
            for (int kc = 0; kc < KC; ++kc)
                hfrag[kc] = *(const frag8*)&hnew[lane & 15][kc * 32 + (lane >> 4) * 8];

            facc4 aG0 = {0.f, 0.f, 0.f, 0.f};
            facc4 aG1 = {0.f, 0.f, 0.f, 0.f};
            facc4 aM0 = {0.f, 0.f, 0.f, 0.f};
            facc4 aM1 = {0.f, 0.f, 0.f, 0.f};
            #pragma unroll
            for (int kc = 0; kc < KC; ++kc) {
                aG0 = __builtin_amdgcn_mfma_f32_16x16x32_bf16(hfrag[kc], wG0[kc], aG0, 0, 0, 0);
                aG1 = __builtin_amdgcn_mfma_f32_16x16x32_bf16(hfrag[kc], wG1[kc], aG1, 0, 0, 0);
                aM0 = __builtin_amdgcn_mfma_f32_16x16x32_bf16(hfrag[kc], wM0[kc], aM0, 0, 0, 0);
                aM1 = __builtin_amdgcn_mfma_f32_16x16x32_bf16(hfrag[kc], wM1[kc], aM1, 0, 0, 0);
            }
            const int q = lane >> 4;
            const int c0 = w * 16 + (lane & 15);
            const int c1 = (w + 8) * 16 + (lane & 15);
            const float bg0 = bgL[c0], bg1 = bgL[c1];
            #pragma unroll
            for (int i = 0; i < 4; ++i) {
                gmrow[4 * q + i][c0] = f2bf(sigm(aG0[i] + bg0) * aM0[i]);
                gmrow[4 * q + i][c1] = f2bf(sigm(aG1[i] + bg1) * aM1[i]);
            }
        }
        __syncthreads();   // gmrow/hnew ready for next step's A / epilogue
    }

    // ---- Epilogue: hg = h_new(v=31) (in hnew LDS); mu/sigma = hg@w_mu/std + b
    #pragma unroll
    for (int s = 0; s < 2; ++s) {
        const int bi = 2 * w + s, z = lane;              // 1 wave per batch
        float am = 0.f, as = 0.f;
        #pragma unroll 4
        for (int h = 0; h < HH; ++h) {
            const float hv = bf2f(hnew[bi][h]);          // LDS broadcast
            am += hv * ldv(w_mu, (size_t)h * ZZ + z);
            as += hv * ldv(w_std, (size_t)h * ZZ + z);
        }
        stv(out, (size_t)(b0 + bi) * ZZ + z, am + ldv(b_mu, z));
        stv(out, (size_t)BB * ZZ + (size_t)(b0 + bi) * ZZ + z, as + ldv(b_std, z));
    }
}

extern "C" void kernel_launch(void* const* d_in, const int* in_sizes, int n_in,
                              void* d_out, int out_size, void* d_ws, size_t ws_size,
                              hipStream_t stream)
{
    unsigned short* whh_p = (unsigned short*)d_ws;
    unsigned short* wgm_p = whh_p + WHH_ELEMS;
    float* wihG = (float*)(wgm_p + WGM_ELEMS);             // byte off 655360 (16B aligned)
    unsigned short* gm_base = (unsigned short*)((char*)d_ws + GM_BYTE_OFF);

    // dtype flag lives in the last aligned 4 bytes of ws
    size_t flag_off = (ws_size >= 8) ? ((ws_size - 4) & ~(size_t)3) : 0;
    int* flag = (int*)((char*)d_ws + flag_off);

    // how many blocks' gm slabs fit between repacked weights and the flag
    long long avail = (long long)flag_off - (long long)GM_BYTE_OFF;
    int cb = (int)(avail / SLAB_BYTES);
    if (cb < 1) cb = 1;                                    // degenerate ws: best effort
    if (cb > BB / BT) cb = BB / BT;

    detect_dtype<<<dim3(1), 256, 0, stream>>>((const unsigned short*)d_in[2], flag);

    // 190 blocks = 640 weight frags * 64 lanes + 7680 wihG elems, exactly
    repack_weights<float><<<dim3(190), 256, 0, stream>>>(
        (const float*)d_in[3], (const float*)d_in[6], (const float*)d_in[8],
        (const float*)d_in[2], (const float*)d_in[4],
        whh_p, wgm_p, wihG, flag, 1);
    repack_weights<unsigned short><<<dim3(190), 256, 0, stream>>>(
        (const unsigned short*)d_in[3], (const unsigned short*)d_in[6],
        (const unsigned short*)d_in[8], (const unsigned short*)d_in[2],
        (const unsigned short*)d_in[4],
        whh_p, wgm_p, wihG, flag, 0);

    const int nblk = BB / BT;                              // 128
    for (int blk0 = 0; blk0 < nblk; blk0 += cb) {
        int g = nblk - blk0; if (g > cb) g = cb;
        vae_main<float><<<dim3(g), 512, 0, stream>>>(
            (const float*)d_in[0], (const int*)d_in[1],
            (const float*)d_in[5], (const float*)d_in[7],
            (const float*)d_in[9], (const float*)d_in[10],
            (const float*)d_in[11], (const float*)d_in[12],
            whh_p, wgm_p, wihG, gm_base, (float*)d_out, blk0 * BT, flag, 1);
        vae_main<unsigned short><<<dim3(g), 512, 0, stream>>>(
            (const unsigned short*)d_in[0], (const int*)d_in[1],
            (const unsigned short*)d_in[5], (const unsigned short*)d_in[7],
            (const unsigned short*)d_in[9], (const unsigned short*)d_in[10],
            (const unsigned short*)d_in[11], (const unsigned short*)d_in[12],
            whh_p, wgm_p, wihG, gm_base, (unsigned short*)d_out, blk0 * BT, flag, 0);
    }
}

// Round 3
// 570.114 us; speedup vs baseline: 1.2790x; 1.2790x over previous
//
#include <hip/hip_runtime.h>

// LogicVAE: graph-GRU VAE encoder. B=2048,N=32,V=10,H=256,Z=64.
// gm[b,n] = sigmoid(h@w_gate+b_gate)*(h@w_map) is a pure function of the FINAL
// hidden[b,n] (adj strictly upper-tri), so it's computed once per node.
// R8 = R6 minus register-pinning. Evidence across R5/R6/R7: EVERY attempt to
// pin wgm fragment tiles in VGPRs spilled to scratch (WRITE 91-120MB, scratch
// working set ~92MB > 32MB L2 -> FETCH 1.2-1.4GB of HBM churn). R7 also showed
// BT=16's 128 blocks idle half the GPU (occ 12%, 649us). So:
//  - BT=8, 1024 threads, 256 blocks (full occupancy, R6 structure)
//  - gm state entirely in LDS (gmAll 128KB): no gm global traffic, phase-A
//    neighbor gathers are ~120cy LDS reads
//  - phase D STREAMS wG/wM fragments from L2 like phase B streams whh;
//    registers ~<100 -> zero scratch; weight streams (640KB/XCD) L2-resident
//  - w_ih as fp32 (w_ih+b_ih)-folded global table (30KB, L1/L2-resident)
//  - fp32 agg overlays dead A-rows 8..15 of aggbf/hnew (C-rows 8..15 unused)
// LDS: 131072+8448+8448+1024+1024+3072+1024 = 154112 B (1 blk/CU, 16 waves).

#define BB 2048
#define NN 32
#define VV 10
#define HH 256
#define ZZ 64
#define BT 8      // batches per block
#define KC 8      // K chunks: 256/32
#define NT1 48    // 768/16 col tiles (w_hh)
#define NT2 32    // 512/16 col tiles (w_gate||w_map)
#define WHH_ELEMS (NT1 * KC * 64 * 8)             // 196608 ushorts (384 KB)
#define WGM_ELEMS (NT2 * KC * 64 * 8)             // 131072 ushorts (256 KB)

typedef __attribute__((ext_vector_type(8))) short frag8;            // 8 bf16 (4 VGPR)
typedef __attribute__((ext_vector_type(4))) float facc4;            // MFMA accum
typedef __attribute__((ext_vector_type(4))) unsigned short us4;     // 8B LDS load

__device__ __forceinline__ float bf2f(unsigned short u) {
    unsigned int x = ((unsigned int)u) << 16;
    return __builtin_bit_cast(float, x);
}
__device__ __forceinline__ unsigned short f2bf(float f) {
    unsigned int x = __builtin_bit_cast(unsigned int, f);
    x += 0x7FFFu + ((x >> 16) & 1u);
    return (unsigned short)(x >> 16);
}
__device__ __forceinline__ float sigm(float x) { return 1.0f / (1.0f + __expf(-x)); }
__device__ __forceinline__ float ldv(const float* p, size_t i) { return p[i]; }
__device__ __forceinline__ float ldv(const unsigned short* p, size_t i) { return bf2f(p[i]); }
__device__ __forceinline__ void stv(float* p, size_t i, float v) { p[i] = v; }
__device__ __forceinline__ void stv(unsigned short* p, size_t i, float v) { p[i] = f2bf(v); }

// flag=1 => buffers are fp32, flag=0 => bf16. Integer-only tests (fast-math safe).
__global__ void detect_dtype(const unsigned short* __restrict__ w, int* flag) {
    __shared__ int zc, bc;
    if (threadIdx.x == 0) { zc = 0; bc = 0; }
    __syncthreads();
    int z = 0, b = 0;
    for (int i = threadIdx.x; i < 2048; i += 256) {
        unsigned short lo = w[2 * i];            // fp32: low mantissa half / bf16: a value
        if (lo == 0) z++;                        // bf16-rounded fp32 storage => all zero
        unsigned e = (lo >> 7) & 0xFFu;          // bf16 exponent field
        if (e >= 0x86u) b++;                     // |x|>=128 or NaN: impossible for N(0,.05) bf16
    }
    atomicAdd(&zc, z); atomicAdd(&bc, b);
    __syncthreads();
    if (threadIdx.x == 0) *flag = (bc > 0 || zc > 512) ? 1 : 0;
}

// Repack w_hh (256x768) and w_gate||w_map (256x512) into bf16 MFMA B-fragment
// order: frag f=jt*KC+kc; elem[(f*64+lane)*8+j] = W[kc*32+(lane>>4)*8+j][jt*16+(lane&15)]
// Tail threads build wihG[10][768] = fp32(w_ih + b_ih) folded table.
template <typename T>
__global__ void repack_weights(const T* __restrict__ w_hh,
                               const T* __restrict__ w_gate,
                               const T* __restrict__ w_map,
                               const T* __restrict__ w_ih,
                               const T* __restrict__ b_ih,
                               unsigned short* __restrict__ whh_p,
                               unsigned short* __restrict__ wgm_p,
                               float* __restrict__ wihG,
                               const int* __restrict__ flag, int want) {
    if (*flag != want) return;
    int t = blockIdx.x * blockDim.x + threadIdx.x;
    int lane = t & 63;
    int frag = t >> 6;                  // 0..759
    int kbase = (lane >> 4) * 8;
    if (frag < NT1 * KC) {
        int jt = frag / KC, kc = frag % KC;
        int col = jt * 16 + (lane & 15);
        unsigned short* dst = whh_p + ((size_t)frag * 64 + lane) * 8;
        #pragma unroll
        for (int j = 0; j < 8; ++j)
            dst[j] = f2bf(ldv(w_hh, (size_t)(kc * 32 + kbase + j) * 768 + col));
    } else if (frag < (NT1 + NT2) * KC) {
        int f2 = frag - NT1 * KC;
        int jt = f2 / KC, kc = f2 % KC;
        int col = jt * 16 + (lane & 15);
        unsigned short* dst = wgm_p + ((size_t)f2 * 64 + lane) * 8;
        #pragma unroll
        for (int j = 0; j < 8; ++j) {
            int k = kc * 32 + kbase + j;
            dst[j] = f2bf((col < HH) ? ldv(w_gate, (size_t)k * HH + col)
                                     : ldv(w_map, (size_t)k * HH + (col - HH)));
        }
    } else {
        int idx = t - (NT1 + NT2) * KC * 64;     // 0..7679 with grid=190
        if (idx < VV * 768) {
            int c = idx % 768;
            wihG[idx] = ldv(w_ih, (size_t)idx) + ldv(b_ih, (size_t)c);
        }
    }
}

template <typename T>
__global__ __launch_bounds__(1024, 4) void vae_main(
    const T* __restrict__ adj,
    const int* __restrict__ ntypes,
    const T* __restrict__ b_hh,
    const T* __restrict__ b_gate,
    const T* __restrict__ w_mu,
    const T* __restrict__ b_mu,
    const T* __restrict__ w_std,
    const T* __restrict__ b_std,
    const unsigned short* __restrict__ whh_p,
    const unsigned short* __restrict__ wgm_p,
    const float* __restrict__ wihG,
    T* __restrict__ out,
    const int* __restrict__ flag, int want)
{
    if (*flag != want) return;

    __shared__ __align__(16) unsigned short gmAll[BT][NN][HH]; // gm state (128 KB)
    __shared__ __align__(16) unsigned short aggbf[16][264];    // MFMA A src rows 0..7
    __shared__ __align__(16) unsigned short hnew[16][264];     // MFMA A src rows 0..7
    __shared__ unsigned int  amask[BT][NN];                    // adj bitmasks (1 KB)
    __shared__ int           ntva[BT][NN];                     // node types (1 KB)
    __shared__ __align__(16) float bhhL[768];                  // b_hh (3 KB)
    __shared__ float bgL[HH];                                  // b_gate (1 KB)

    // fp32 agg overlays the dead rows 8..15 (those MFMA C-rows are discarded;
    // garbage A-rows 8..15 only pollute discarded C-rows 8..15).
    float* const aggA = (float*)&aggbf[8][0];   // bi 0..3: 4x256 fp32 (4 KB)
    float* const aggB = (float*)&hnew[8][0];    // bi 4..7

    const int tid  = threadIdx.x;
    const int lane = tid & 63;
    const int w    = tid >> 6;          // wave 0..15
    const int b0   = blockIdx.x * BT;

    const frag8* whh8 = (const frag8*)whh_p;
    const frag8* wgm8 = (const frag8*)wgm_p;

    // ---- one-time preload ----
    if (tid < 256) {                         // adj -> bitmask (adj is exactly {0,1})
        int bi = tid >> 5, vv = tid & 31;
        unsigned m = 0;
        for (int n = 0; n < NN; ++n)
            if (ldv(adj, ((size_t)(b0 + bi) * NN + n) * NN + vv) != 0.0f) m |= (1u << n);
        amask[bi][vv] = m;
    } else if (tid < 512) {
        int idx = tid - 256;
        int bi = idx >> 5, vv = idx & 31;
        ntva[bi][vv] = ntypes[(b0 + bi) * NN + vv];
    }
    for (int i = tid; i < 768; i += 1024) bhhL[i] = ldv(b_hh, i);
    if (tid < HH) bgL[tid] = ldv(b_gate, tid);
    __syncthreads();

    for (int v = 0; v < NN; ++v) {
        // ---- A (waves 0..7): agg over neighbor gm rows, all from LDS.
        if (w < BT) {
            const int bi = w;
            const int h4 = lane * 4;
            unsigned m = amask[bi][v];       // wave-uniform
            float a0 = 0.f, a1 = 0.f, a2 = 0.f, a3 = 0.f;
            const unsigned short* rb = &gmAll[bi][0][0] + h4;
            while (m) {                      // 2-wide to keep 2 ds_reads in flight
                const int n0 = __builtin_ctz(m); m &= m - 1;
                const us4 g0 = *(const us4*)(rb + n0 * HH);
                if (m) {
                    const int n1 = __builtin_ctz(m); m &= m - 1;
                    const us4 g1 = *(const us4*)(rb + n1 * HH);
                    a0 += bf2f(g0.x) + bf2f(g1.x);
                    a1 += bf2f(g0.y) + bf2f(g1.y);
                    a2 += bf2f(g0.z) + bf2f(g1.z);
                    a3 += bf2f(g0.w) + bf2f(g1.w);
                } else {
                    a0 += bf2f(g0.x); a1 += bf2f(g0.y);
                    a2 += bf2f(g0.z); a3 += bf2f(g0.w);
                }
            }
            float* ap = (bi < 4) ? (aggA + bi * 256) : (aggB + (bi - 4) * 256);
            *(float4*)(ap + h4) = make_float4(a0, a1, a2, a3);
            ushort4 ab; ab.x = f2bf(a0); ab.y = f2bf(a1); ab.z = f2bf(a2); ab.w = f2bf(a3);
            *(ushort4*)&aggbf[bi][h4] = ab;
        }
        __syncthreads();

        // ---- B: gh = agg @ w_hh (MFMA) fused with GRU elementwise -> hnew
        {
            const int t = w;                             // triplet: cols t, t+16, t+32
            const int col = t * 16 + (lane & 15);
            const int q = lane >> 4;                     // C row = 4q+i, valid q<2
            float xr[4], xz[4], xn[4];                   // x@w_ih + b_ih (fp32, folded)
            if (q < 2) {
                #pragma unroll
                for (int i = 0; i < 4; ++i) {
                    const float* wr = wihG + (size_t)ntva[4 * q + i][v] * 768 + col;
                    xr[i] = wr[0]; xz[i] = wr[256]; xn[i] = wr[512];
                }
            }
            frag8 afrag[KC];
            #pragma unroll
            for (int kc = 0; kc < KC; ++kc)
                afrag[kc] = *(const frag8*)&aggbf[lane & 15][kc * 32 + (lane >> 4) * 8];

            facc4 aR = {0.f, 0.f, 0.f, 0.f};
            facc4 aZ = {0.f, 0.f, 0.f, 0.f};
            facc4 aN = {0.f, 0.f, 0.f, 0.f};
            const frag8* pR = whh8 + (size_t)(t     ) * (KC * 64) + lane;
            const frag8* pZ = whh8 + (size_t)(t + 16) * (KC * 64) + lane;
            const frag8* pN = whh8 + (size_t)(t + 32) * (KC * 64) + lane;
            #pragma unroll
            for (int kc = 0; kc < KC; ++kc) {
                aR = __builtin_amdgcn_mfma_f32_16x16x32_bf16(afrag[kc], pR[kc * 64], aR, 0, 0, 0);
                aZ = __builtin_amdgcn_mfma_f32_16x16x32_bf16(afrag[kc], pZ[kc * 64], aZ, 0, 0, 0);
                aN = __builtin_amdgcn_mfma_f32_16x16x32_bf16(afrag[kc], pN[kc * 64], aN, 0, 0, 0);
            }
            if (q < 2) {
                const float bhr = bhhL[col], bhz = bhhL[col + 256], bhn = bhhL[col + 512];
                const float* ap = (q == 0) ? aggA : aggB;
                #pragma unroll
                for (int i = 0; i < 4; ++i) {
                    const float r = sigm(xr[i] + aR[i] + bhr);
                    const float z = sigm(xz[i] + aZ[i] + bhz);
                    const float n = tanhf(xn[i] + r * (aN[i] + bhn));
                    hnew[4 * q + i][col] = f2bf((1.f - z) * n + z * ap[i * 256 + col]);
                }
            }
        }
        __syncthreads();

        // ---- D: gm_v = sigmoid(h@w_gate+b_gate) * (h@w_map) -> gmAll[.][v]
        //      (streamed from L2 -- register-pinning these spilled in R5/R6/R7)
        {
            frag8 hfrag[KC];
            #pragma unroll
            for (int kc = 0; kc < KC; ++kc)
                hfrag[kc] = *(const frag8*)&hnew[lane & 15][kc * 32 + (lane >> 4) * 8];

            facc4 aG = {0.f, 0.f, 0.f, 0.f};
            facc4 aM = {0.f, 0.f, 0.f, 0.f};
            const frag8* pG = wgm8 + (size_t)(w     ) * (KC * 64) + lane;
            const frag8* pM = wgm8 + (size_t)(w + 16) * (KC * 64) + lane;
            #pragma unroll
            for (int kc = 0; kc < KC; ++kc) {
                aG = __builtin_amdgcn_mfma_f32_16x16x32_bf16(hfrag[kc], pG[kc * 64], aG, 0, 0, 0);
                aM = __builtin_amdgcn_mfma_f32_16x16x32_bf16(hfrag[kc], pM[kc * 64], aM, 0, 0, 0);
            }
            const int col = w * 16 + (lane & 15);        // 0..255
            const int q = lane >> 4;
            if (q < 2) {
                const float bg = bgL[col];
                #pragma unroll
                for (int i = 0; i < 4; ++i)
                    gmAll[4 * q + i][v][col] = f2bf(sigm(aG[i] + bg) * aM[i]);
            }
        }
        __syncthreads();   // gmAll row v / hnew ready for next step's A / epilogue
    }

    // ---- Epilogue: hg = h_new(v=31) (in hnew LDS); mu/sigma = hg@w_mu/std + b
    {
        const int bi = w >> 1, half = w & 1, z = lane;   // 2 waves per batch
        float am = 0.f, as = 0.f;
        const int h0 = half * 128;
        #pragma unroll 4
        for (int h = h0; h < h0 + 128; ++h) {
            const float hv = bf2f(hnew[bi][h]);          // LDS broadcast
            am += hv * ldv(w_mu, (size_t)h * ZZ + z);
            as += hv * ldv(w_std, (size_t)h * ZZ + z);
        }
        float* sc = (bi < 4) ? (aggA + bi * 256) : (aggB + (bi - 4) * 256);
        sc[half * 64 + z]       = am;                    // overlay region as scratch
        sc[128 + half * 64 + z] = as;
    }
    __syncthreads();
    if (w < BT) {
        const int bi = w, z = lane;
        const float* sc = (bi < 4) ? (aggA + bi * 256) : (aggB + (bi - 4) * 256);
        const float am = sc[z] + sc[64 + z] + ldv(b_mu, z);
        const float as = sc[128 + z] + sc[192 + z] + ldv(b_std, z);
        stv(out, (size_t)(b0 + bi) * ZZ + z, am);
        stv(out, (size_t)BB * ZZ + (size_t)(b0 + bi) * ZZ + z, as);
    }
}

extern "C" void kernel_launch(void* const* d_in, const int* in_sizes, int n_in,
                              void* d_out, int out_size, void* d_ws, size_t ws_size,
                              hipStream_t stream)
{
    unsigned short* whh_p = (unsigned short*)d_ws;
    unsigned short* wgm_p = whh_p + WHH_ELEMS;
    float* wihG = (float*)(wgm_p + WGM_ELEMS);             // byte off 655360 (16B aligned)

    // dtype flag lives in the last aligned 4 bytes of ws
    size_t flag_off = (ws_size >= 8) ? ((ws_size - 4) & ~(size_t)3) : 0;
    int* flag = (int*)((char*)d_ws + flag_off);

    detect_dtype<<<dim3(1), 256, 0, stream>>>((const unsigned short*)d_in[2], flag);

    // 190 blocks = 640 weight frags * 64 lanes + 7680 wihG elems, exactly
    repack_weights<float><<<dim3(190), 256, 0, stream>>>(
        (const float*)d_in[3], (const float*)d_in[6], (const float*)d_in[8],
        (const float*)d_in[2], (const float*)d_in[4],
        whh_p, wgm_p, wihG, flag, 1);
    repack_weights<unsigned short><<<dim3(190), 256, 0, stream>>>(
        (const unsigned short*)d_in[3], (const unsigned short*)d_in[6],
        (const unsigned short*)d_in[8], (const unsigned short*)d_in[2],
        (const unsigned short*)d_in[4],
        whh_p, wgm_p, wihG, flag, 0);

    vae_main<float><<<dim3(BB / BT), 1024, 0, stream>>>(
        (const float*)d_in[0], (const int*)d_in[1],
        (const float*)d_in[5], (const float*)d_in[7],
        (const float*)d_in[9], (const float*)d_in[10],
        (const float*)d_in[11], (const float*)d_in[12],
        whh_p, wgm_p, wihG, (float*)d_out, flag, 1);
    vae_main<unsigned short><<<dim3(BB / BT), 1024, 0, stream>>>(
        (const unsigned short*)d_in[0], (const int*)d_in[1],
        (const unsigned short*)d_in[5], (const unsigned short*)d_in[7],
        (const unsigned short*)d_in[9], (const unsigned short*)d_in[10],
        (const unsigned short*)d_in[11], (const unsigned short*)d_in[12],
        whh_p, wgm_p, wihG, (unsigned short*)d_out, flag, 0);
}

// Round 4
// 529.837 us; speedup vs baseline: 1.3762x; 1.0760x over previous
//
#include <hip/hip_runtime.h>

// LogicVAE: graph-GRU VAE encoder. B=2048,N=32,V=10,H=256,Z=64.
// gm[b,n] = sigmoid(h@w_gate+b_gate)*(h@w_map) is a pure function of the FINAL
// hidden[b,n] (adj strictly upper-tri), so it's computed once per node.
// R9 = R8 + a REAL wgm register pin. Evidence: R6 (pin) and R8 (no pin) had
// bit-identical counters (VGPR=64, FETCH 1.37GB) -> the compiler rematerialized
// the "pinned" loads in-loop; the pin never existed. Cost model: 640KB of
// weight fragments re-read per CU per step (whh 384 + wgm 256) is the wall
// (L2-share ~153us + 1.37GB L2-miss ~440us). This round:
//  - wG/wM loaded once, then made opaque via asm volatile redefinition ->
//    not rematerializable; must live in regs for all 32 steps (64 VGPRs)
//  - afrag/hfrag per-kc (4 regs live, not 32) + wihG gather moved after MFMAs
//    to fit the 128-reg cap (1024 thr, 4 waves/EU)
//  - everything else identical to R8 (clean A/B): BT=8, 256 blocks, gmAll in
//    LDS 128KB, fp32 agg overlaying dead A-rows 8..15
// Watch: VGPR_Count must rise to ~112-128 (pin real); WRITE must stay ~91MB
// (no spill); FETCH should drop to ~0.85GB.

#define BB 2048
#define NN 32
#define VV 10
#define HH 256
#define ZZ 64
#define BT 8      // batches per block
#define KC 8      // K chunks: 256/32
#define NT1 48    // 768/16 col tiles (w_hh)
#define NT2 32    // 512/16 col tiles (w_gate||w_map)
#define WHH_ELEMS (NT1 * KC * 64 * 8)             // 196608 ushorts (384 KB)
#define WGM_ELEMS (NT2 * KC * 64 * 8)             // 131072 ushorts (256 KB)

typedef __attribute__((ext_vector_type(8))) short frag8;            // 8 bf16 (4 VGPR)
typedef __attribute__((ext_vector_type(4))) float facc4;            // MFMA accum
typedef __attribute__((ext_vector_type(4))) unsigned short us4;     // 8B LDS load
typedef __attribute__((ext_vector_type(4))) unsigned int ui4;       // asm-pin carrier

__device__ __forceinline__ float bf2f(unsigned short u) {
    unsigned int x = ((unsigned int)u) << 16;
    return __builtin_bit_cast(float, x);
}
__device__ __forceinline__ unsigned short f2bf(float f) {
    unsigned int x = __builtin_bit_cast(unsigned int, f);
    x += 0x7FFFu + ((x >> 16) & 1u);
    return (unsigned short)(x >> 16);
}
__device__ __forceinline__ float sigm(float x) { return 1.0f / (1.0f + __expf(-x)); }
__device__ __forceinline__ float ldv(const float* p, size_t i) { return p[i]; }
__device__ __forceinline__ float ldv(const unsigned short* p, size_t i) { return bf2f(p[i]); }
__device__ __forceinline__ void stv(float* p, size_t i, float v) { p[i] = v; }
__device__ __forceinline__ void stv(unsigned short* p, size_t i, float v) { p[i] = f2bf(v); }

// Opaque redefinition: breaks the value's provenance so the compiler cannot
// rematerialize it from the original global load; it must stay resident.
__device__ __forceinline__ void pin_frag(frag8& f) {
    ui4 t = __builtin_bit_cast(ui4, f);
    asm volatile("" : "+v"(t));
    f = __builtin_bit_cast(frag8, t);
}

// flag=1 => buffers are fp32, flag=0 => bf16. Integer-only tests (fast-math safe).
__global__ void detect_dtype(const unsigned short* __restrict__ w, int* flag) {
    __shared__ int zc, bc;
    if (threadIdx.x == 0) { zc = 0; bc = 0; }
    __syncthreads();
    int z = 0, b = 0;
    for (int i = threadIdx.x; i < 2048; i += 256) {
        unsigned short lo = w[2 * i];            // fp32: low mantissa half / bf16: a value
        if (lo == 0) z++;                        // bf16-rounded fp32 storage => all zero
        unsigned e = (lo >> 7) & 0xFFu;          // bf16 exponent field
        if (e >= 0x86u) b++;                     // |x|>=128 or NaN: impossible for N(0,.05) bf16
    }
    atomicAdd(&zc, z); atomicAdd(&bc, b);
    __syncthreads();
    if (threadIdx.x == 0) *flag = (bc > 0 || zc > 512) ? 1 : 0;
}

// Repack w_hh (256x768) and w_gate||w_map (256x512) into bf16 MFMA B-fragment
// order: frag f=jt*KC+kc; elem[(f*64+lane)*8+j] = W[kc*32+(lane>>4)*8+j][jt*16+(lane&15)]
// Tail threads build wihG[10][768] = fp32(w_ih + b_ih) folded table.
template <typename T>
__global__ void repack_weights(const T* __restrict__ w_hh,
                               const T* __restrict__ w_gate,
                               const T* __restrict__ w_map,
                               const T* __restrict__ w_ih,
                               const T* __restrict__ b_ih,
                               unsigned short* __restrict__ whh_p,
                               unsigned short* __restrict__ wgm_p,
                               float* __restrict__ wihG,
                               const int* __restrict__ flag, int want) {
    if (*flag != want) return;
    int t = blockIdx.x * blockDim.x + threadIdx.x;
    int lane = t & 63;
    int frag = t >> 6;                  // 0..759
    int kbase = (lane >> 4) * 8;
    if (frag < NT1 * KC) {
        int jt = frag / KC, kc = frag % KC;
        int col = jt * 16 + (lane & 15);
        unsigned short* dst = whh_p + ((size_t)frag * 64 + lane) * 8;
        #pragma unroll
        for (int j = 0; j < 8; ++j)
            dst[j] = f2bf(ldv(w_hh, (size_t)(kc * 32 + kbase + j) * 768 + col));
    } else if (frag < (NT1 + NT2) * KC) {
        int f2 = frag - NT1 * KC;
        int jt = f2 / KC, kc = f2 % KC;
        int col = jt * 16 + (lane & 15);
        unsigned short* dst = wgm_p + ((size_t)f2 * 64 + lane) * 8;
        #pragma unroll
        for (int j = 0; j < 8; ++j) {
            int k = kc * 32 + kbase + j;
            dst[j] = f2bf((col < HH) ? ldv(w_gate, (size_t)k * HH + col)
                                     : ldv(w_map, (size_t)k * HH + (col - HH)));
        }
    } else {
        int idx = t - (NT1 + NT2) * KC * 64;     // 0..7679 with grid=190
        if (idx < VV * 768) {
            int c = idx % 768;
            wihG[idx] = ldv(w_ih, (size_t)idx) + ldv(b_ih, (size_t)c);
        }
    }
}

template <typename T>
__global__ __launch_bounds__(1024, 4) void vae_main(
    const T* __restrict__ adj,
    const int* __restrict__ ntypes,
    const T* __restrict__ b_hh,
    const T* __restrict__ b_gate,
    const T* __restrict__ w_mu,
    const T* __restrict__ b_mu,
    const T* __restrict__ w_std,
    const T* __restrict__ b_std,
    const unsigned short* __restrict__ whh_p,
    const unsigned short* __restrict__ wgm_p,
    const float* __restrict__ wihG,
    T* __restrict__ out,
    const int* __restrict__ flag, int want)
{
    if (*flag != want) return;

    __shared__ __align__(16) unsigned short gmAll[BT][NN][HH]; // gm state (128 KB)
    __shared__ __align__(16) unsigned short aggbf[16][264];    // MFMA A src rows 0..7
    __shared__ __align__(16) unsigned short hnew[16][264];     // MFMA A src rows 0..7
    __shared__ unsigned int  amask[BT][NN];                    // adj bitmasks (1 KB)
    __shared__ int           ntva[BT][NN];                     // node types (1 KB)
    __shared__ __align__(16) float bhhL[768];                  // b_hh (3 KB)
    __shared__ float bgL[HH];                                  // b_gate (1 KB)

    // fp32 agg overlays the dead rows 8..15 (those MFMA C-rows are discarded;
    // garbage A-rows 8..15 only pollute discarded C-rows 8..15).
    float* const aggA = (float*)&aggbf[8][0];   // bi 0..3: 4x256 fp32 (4 KB)
    float* const aggB = (float*)&hnew[8][0];    // bi 4..7

    const int tid  = threadIdx.x;
    const int lane = tid & 63;
    const int w    = tid >> 6;          // wave 0..15
    const int b0   = blockIdx.x * BT;

    const frag8* whh8 = (const frag8*)whh_p;
    const frag8* wgm8 = (const frag8*)wgm_p;

    // ---- one-time preload ----
    if (tid < 256) {                         // adj -> bitmask (adj is exactly {0,1})
        int bi = tid >> 5, vv = tid & 31;
        unsigned m = 0;
        for (int n = 0; n < NN; ++n)
            if (ldv(adj, ((size_t)(b0 + bi) * NN + n) * NN + vv) != 0.0f) m |= (1u << n);
        amask[bi][vv] = m;
    } else if (tid < 512) {
        int idx = tid - 256;
        int bi = idx >> 5, vv = idx & 31;
        ntva[bi][vv] = ntypes[(b0 + bi) * NN + vv];
    }
    for (int i = tid; i < 768; i += 1024) bhhL[i] = ldv(b_hh, i);
    if (tid < HH) bgL[tid] = ldv(b_gate, tid);

    // ---- pin phase-D tiles in regs for all 32 steps (64 VGPRs/thread).
    //      asm redefinition makes them non-rematerializable.
    frag8 wG[KC], wM[KC];
    {
        const frag8* pG = wgm8 + (size_t)(w     ) * (KC * 64) + lane;
        const frag8* pM = wgm8 + (size_t)(w + 16) * (KC * 64) + lane;
        #pragma unroll
        for (int kc = 0; kc < KC; ++kc) { wG[kc] = pG[kc * 64]; wM[kc] = pM[kc * 64]; }
        #pragma unroll
        for (int kc = 0; kc < KC; ++kc) { pin_frag(wG[kc]); pin_frag(wM[kc]); }
    }
    __syncthreads();

    for (int v = 0; v < NN; ++v) {
        // ---- A (waves 0..7): agg over neighbor gm rows, all from LDS.
        if (w < BT) {
            const int bi = w;
            const int h4 = lane * 4;
            unsigned m = amask[bi][v];       // wave-uniform
            float a0 = 0.f, a1 = 0.f, a2 = 0.f, a3 = 0.f;
            const unsigned short* rb = &gmAll[bi][0][0] + h4;
            while (m) {                      // 2-wide to keep 2 ds_reads in flight
                const int n0 = __builtin_ctz(m); m &= m - 1;
                const us4 g0 = *(const us4*)(rb + n0 * HH);
                if (m) {
                    const int n1 = __builtin_ctz(m); m &= m - 1;
                    const us4 g1 = *(const us4*)(rb + n1 * HH);
                    a0 += bf2f(g0.x) + bf2f(g1.x);
                    a1 += bf2f(g0.y) + bf2f(g1.y);
                    a2 += bf2f(g0.z) + bf2f(g1.z);
                    a3 += bf2f(g0.w) + bf2f(g1.w);
                } else {
                    a0 += bf2f(g0.x); a1 += bf2f(g0.y);
                    a2 += bf2f(g0.z); a3 += bf2f(g0.w);
                }
            }
            float* ap = (bi < 4) ? (aggA + bi * 256) : (aggB + (bi - 4) * 256);
            *(float4*)(ap + h4) = make_float4(a0, a1, a2, a3);
            ushort4 ab; ab.x = f2bf(a0); ab.y = f2bf(a1); ab.z = f2bf(a2); ab.w = f2bf(a3);
            *(ushort4*)&aggbf[bi][h4] = ab;
        }
        __syncthreads();

        // ---- B: gh = agg @ w_hh (MFMA) fused with GRU elementwise -> hnew
        {
            const int t = w;                             // triplet: cols t, t+16, t+32
            const int col = t * 16 + (lane & 15);
            const int q = lane >> 4;                     // C row = 4q+i, valid q<2

            facc4 aR = {0.f, 0.f, 0.f, 0.f};
            facc4 aZ = {0.f, 0.f, 0.f, 0.f};
            facc4 aN = {0.f, 0.f, 0.f, 0.f};
            const frag8* pR = whh8 + (size_t)(t     ) * (KC * 64) + lane;
            const frag8* pZ = whh8 + (size_t)(t + 16) * (KC * 64) + lane;
            const frag8* pN = whh8 + (size_t)(t + 32) * (KC * 64) + lane;
            #pragma unroll
            for (int kc = 0; kc < KC; ++kc) {            // per-kc afrag: 4 regs live
                const frag8 af = *(const frag8*)&aggbf[lane & 15][kc * 32 + (lane >> 4) * 8];
                aR = __builtin_amdgcn_mfma_f32_16x16x32_bf16(af, pR[kc * 64], aR, 0, 0, 0);
                aZ = __builtin_amdgcn_mfma_f32_16x16x32_bf16(af, pZ[kc * 64], aZ, 0, 0, 0);
                aN = __builtin_amdgcn_mfma_f32_16x16x32_bf16(af, pN[kc * 64], aN, 0, 0, 0);
            }
            if (q < 2) {
                const float bhr = bhhL[col], bhz = bhhL[col + 256], bhn = bhhL[col + 512];
                const float* ap = (q == 0) ? aggA : aggB;
                #pragma unroll
                for (int i = 0; i < 4; ++i) {
                    const float* wr = wihG + (size_t)ntva[4 * q + i][v] * 768 + col;
                    const float r = sigm(wr[0]   + aR[i] + bhr);
                    const float z = sigm(wr[256] + aZ[i] + bhz);
                    const float n = tanhf(wr[512] + r * (aN[i] + bhn));
                    hnew[4 * q + i][col] = f2bf((1.f - z) * n + z * ap[i * 256 + col]);
                }
            }
        }
        __syncthreads();

        // ---- D: gm_v = sigmoid(h@w_gate+b_gate) * (h@w_map) -> gmAll[.][v]
        //      (wG/wM pinned in registers: zero global traffic in this phase)
        {
            facc4 aG = {0.f, 0.f, 0.f, 0.f};
            facc4 aM = {0.f, 0.f, 0.f, 0.f};
            #pragma unroll
            for (int kc = 0; kc < KC; ++kc) {            // per-kc hfrag: 4 regs live
                const frag8 hf = *(const frag8*)&hnew[lane & 15][kc * 32 + (lane >> 4) * 8];
                aG = __builtin_amdgcn_mfma_f32_16x16x32_bf16(hf, wG[kc], aG, 0, 0, 0);
                aM = __builtin_amdgcn_mfma_f32_16x16x32_bf16(hf, wM[kc], aM, 0, 0, 0);
            }
            const int col = w * 16 + (lane & 15);        // 0..255
            const int q = lane >> 4;
            if (q < 2) {
                const float bg = bgL[col];
                #pragma unroll
                for (int i = 0; i < 4; ++i)
                    gmAll[4 * q + i][v][col] = f2bf(sigm(aG[i] + bg) * aM[i]);
            }
        }
        __syncthreads();   // gmAll row v / hnew ready for next step's A / epilogue
    }

    // ---- Epilogue: hg = h_new(v=31) (in hnew LDS); mu/sigma = hg@w_mu/std + b
    {
        const int bi = w >> 1, half = w & 1, z = lane;   // 2 waves per batch
        float am = 0.f, as = 0.f;
        const int h0 = half * 128;
        #pragma unroll 4
        for (int h = h0; h < h0 + 128; ++h) {
            const float hv = bf2f(hnew[bi][h]);          // LDS broadcast
            am += hv * ldv(w_mu, (size_t)h * ZZ + z);
            as += hv * ldv(w_std, (size_t)h * ZZ + z);
        }
        float* sc = (bi < 4) ? (aggA + bi * 256) : (aggB + (bi - 4) * 256);
        sc[half * 64 + z]       = am;                    // overlay region as scratch
        sc[128 + half * 64 + z] = as;
    }
    __syncthreads();
    if (w < BT) {
        const int bi = w, z = lane;
        const float* sc = (bi < 4) ? (aggA + bi * 256) : (aggB + (bi - 4) * 256);
        const float am = sc[z] + sc[64 + z] + ldv(b_mu, z);
        const float as = sc[128 + z] + sc[192 + z] + ldv(b_std, z);
        stv(out, (size_t)(b0 + bi) * ZZ + z, am);
        stv(out, (size_t)BB * ZZ + (size_t)(b0 + bi) * ZZ + z, as);
    }
}

extern "C" void kernel_launch(void* const* d_in, const int* in_sizes, int n_in,
                              void* d_out, int out_size, void* d_ws, size_t ws_size,
                              hipStream_t stream)
{
    unsigned short* whh_p = (unsigned short*)d_ws;
    unsigned short* wgm_p = whh_p + WHH_ELEMS;
    float* wihG = (float*)(wgm_p + WGM_ELEMS);             // byte off 655360 (16B aligned)

    // dtype flag lives in the last aligned 4 bytes of ws
    size_t flag_off = (ws_size >= 8) ? ((ws_size - 4) & ~(size_t)3) : 0;
    int* flag = (int*)((char*)d_ws + flag_off);

    detect_dtype<<<dim3(1), 256, 0, stream>>>((const unsigned short*)d_in[2], flag);

    // 190 blocks = 640 weight frags * 64 lanes + 7680 wihG elems, exactly
    repack_weights<float><<<dim3(190), 256, 0, stream>>>(
        (const float*)d_in[3], (const float*)d_in[6], (const float*)d_in[8],
        (const float*)d_in[2], (const float*)d_in[4],
        whh_p, wgm_p, wihG, flag, 1);
    repack_weights<unsigned short><<<dim3(190), 256, 0, stream>>>(
        (const unsigned short*)d_in[3], (const unsigned short*)d_in[6],
        (const unsigned short*)d_in[8], (const unsigned short*)d_in[2],
        (const unsigned short*)d_in[4],
        whh_p, wgm_p, wihG, flag, 0);

    vae_main<float><<<dim3(BB / BT), 1024, 0, stream>>>(
        (const float*)d_in[0], (const int*)d_in[1],
        (const float*)d_in[5], (const float*)d_in[7],
        (const float*)d_in[9], (const float*)d_in[10],
        (const float*)d_in[11], (const float*)d_in[12],
        whh_p, wgm_p, wihG, (float*)d_out, flag, 1);
    vae_main<unsigned short><<<dim3(BB / BT), 1024, 0, stream>>>(
        (const unsigned short*)d_in[0], (const int*)d_in[1],
        (const unsigned short*)d_in[5], (const unsigned short*)d_in[7],
        (const unsigned short*)d_in[9], (const unsigned short*)d_in[10],
        (const unsigned short*)d_in[11], (const unsigned short*)d_in[12],
        whh_p, wgm_p, wihG, (unsigned short*)d_out, flag, 0);
}